// Round 10
// baseline (232.838 us; speedup 1.0000x reference)
//
#include <hip/hip_runtime.h>

typedef short short8 __attribute__((ext_vector_type(8)));
typedef short short4v __attribute__((ext_vector_type(4)));
typedef float f32x4 __attribute__((ext_vector_type(4)));

#define B_   16
#define C_   512
#define N_   1024
#define NH_  8
#define CH_  64
#define G_   32
#define CPG_ 16

__device__ inline float b2f(unsigned int u) {
    union { unsigned int i; float f; } v; v.i = u << 16; return v.f;
}
__device__ inline unsigned short f2b(float f) {
    union { float f; unsigned int i; } v; v.f = f;
    unsigned int r = v.i + 0x7fffu + ((v.i >> 16) & 1u);
    return (unsigned short)(r >> 16);
}
__device__ inline unsigned int pack2(float a, float b) {
    return (unsigned int)f2b(a) | ((unsigned int)f2b(b) << 16);
}
__device__ inline unsigned int asu(float f) {
    union { float f; unsigned int i; } v; v.f = f; return v.i;
}
// truncating bf16 pack: [lo16 = hi16(a) | hi16(b)<<16]
__device__ inline unsigned int packtr(float a, float b) {
    return __builtin_amdgcn_perm(asu(b), asu(a), 0x07060302u);
}
// async global->LDS, 16B per lane; LDS dst = wave-uniform base + lane*16
__device__ inline void gload16(const void* g, void* l) {
    __builtin_amdgcn_global_load_lds(
        (const __attribute__((address_space(1))) void*)g,
        (__attribute__((address_space(3))) void*)l, 16, 0, 0);
}

// ------- Kernel 1: GroupNorm (blocks 0-511) | weight fp32->bf16 conv (512-1023) -------
__global__ __launch_bounds__(256) void gnconv_kernel(const float* __restrict__ x,
                                                     const float* __restrict__ nw,
                                                     const float* __restrict__ nb,
                                                     unsigned short* __restrict__ xnT,
                                                     const float* __restrict__ qkvw,
                                                     const float* __restrict__ projw,
                                                     unsigned short* __restrict__ wq,
                                                     unsigned short* __restrict__ wp)
{
    __shared__ float red[8];
    int t = threadIdx.x;

    if (blockIdx.x >= 512) {
        const int NQ = 3 * C_ * C_;
        int idx = (((int)blockIdx.x - 512) * 256 + t) * 8;
        const float* src; unsigned short* dst; int j;
        if (idx < NQ) { src = qkvw;  dst = wq; j = idx; }
        else          { src = projw; dst = wp; j = idx - NQ; }
        float4 u0 = *(const float4*)(src + j);
        float4 u1 = *(const float4*)(src + j + 4);
        uint4 p;
        p.x = pack2(u0.x, u0.y); p.y = pack2(u0.z, u0.w);
        p.z = pack2(u1.x, u1.y); p.w = pack2(u1.z, u1.w);
        *(uint4*)(dst + j) = p;
        return;
    }

    int b = blockIdx.x >> 5, g = blockIdx.x & 31;
    const float* base = x + ((size_t)(b * C_ + g * CPG_)) * N_;

    float s = 0.f, ss = 0.f;
    for (int it = 0; it < 16; ++it) {
        int idx = (it * 256 + t) * 4;
        float4 u = *(const float4*)(base + idx);
        s  += u.x + u.y + u.z + u.w;
        ss += u.x * u.x + u.y * u.y + u.z * u.z + u.w * u.w;
    }
#pragma unroll
    for (int off = 1; off < 64; off <<= 1) {
        s  += __shfl_xor(s, off);
        ss += __shfl_xor(ss, off);
    }
    int wv = t >> 6;
    if ((t & 63) == 0) { red[wv * 2] = s; red[wv * 2 + 1] = ss; }
    __syncthreads();
    s  = red[0] + red[2] + red[4] + red[6];
    ss = red[1] + red[3] + red[5] + red[7];
    float mean = s * (1.f / 16384.f);
    float var  = ss * (1.f / 16384.f) - mean * mean;
    float rstd = rsqrtf(var + 1e-5f);

    float sc[16], sh[16];
#pragma unroll
    for (int ch = 0; ch < 16; ++ch) {
        float wv_ = nw[g * CPG_ + ch];
        float bv_ = nb[g * CPG_ + ch];
        sc[ch] = wv_ * rstd;
        sh[ch] = bv_ - mean * sc[ch];
    }

#pragma unroll
    for (int nbi = 0; nbi < 2; ++nbi) {
        int n = nbi * 512 + t * 2;
        float2 v[16];
#pragma unroll
        for (int ch = 0; ch < 16; ++ch)
            v[ch] = *(const float2*)(base + (size_t)ch * N_ + n);
#pragma unroll
        for (int col = 0; col < 2; ++col) {
            float f[16];
#pragma unroll
            for (int ch = 0; ch < 16; ++ch) {
                float xv = col ? v[ch].y : v[ch].x;
                f[ch] = xv * sc[ch] + sh[ch];
            }
            uint4 o0, o1;
            o0.x = pack2(f[0], f[1]);  o0.y = pack2(f[2], f[3]);
            o0.z = pack2(f[4], f[5]);  o0.w = pack2(f[6], f[7]);
            o1.x = pack2(f[8], f[9]);  o1.y = pack2(f[10], f[11]);
            o1.z = pack2(f[12], f[13]); o1.w = pack2(f[14], f[15]);
            unsigned short* dst = xnT + ((size_t)(b * N_ + n + col)) * C_ + g * CPG_;
            *(uint4*)dst = o0;
            *(uint4*)(dst + 8) = o1;
        }
    }
}

// ------- Kernel 2: QKV GEMM, double-buffered BK=32 pipeline + swapped-operand V path -------
__global__ __launch_bounds__(256) void qkv_kernel(const unsigned short* __restrict__ w,
                                                  const float* __restrict__ bias,
                                                  const unsigned short* __restrict__ xnT,
                                                  unsigned short* __restrict__ qT,
                                                  unsigned short* __restrict__ kT,
                                                  unsigned short* __restrict__ vv)
{
    __shared__ unsigned short Als[2][128 * 32], Bls[2][128 * 32];
    int t = threadIdx.x;
    int n0 = blockIdx.x * 128, m0 = blockIdx.y * 128, b = blockIdx.z;
    int lane = t & 63, wv = t >> 6;
    int l = lane & 15, qd = lane >> 4;
    int wm = (wv >> 1) * 64, wn = (wv & 1) * 64;
    f32x4 acc[4][4] = {};
    const unsigned short* Bbase = xnT + ((size_t)(b * N_ + n0)) * C_;
    int isv = (m0 >= 1024);   // V section: swap MFMA operands

    // staging: wave covers rows [wv*32, wv*32+32); XOR swizzle on 16B blocks
    int lr = lane >> 2, bpos = lane & 3;
    int r0 = wv * 32 + lr, r1 = r0 + 16;
    int c0 = (bpos ^ ((r0 >> 1) & 3)) * 8;
    int c1 = (bpos ^ ((r1 >> 1) & 3)) * 8;
    const unsigned short* gA0 = w + (size_t)(m0 + r0) * C_ + c0;
    const unsigned short* gA1 = w + (size_t)(m0 + r1) * C_ + c1;
    const unsigned short* gB0 = Bbase + (size_t)r0 * C_ + c0;
    const unsigned short* gB1 = Bbase + (size_t)r1 * C_ + c1;
    int lo0 = (wv * 32) * 32, lo1 = (wv * 32 + 16) * 32;
    int aswz = (qd ^ ((l >> 1) & 3)) * 8;

    // prologue: tile 0 -> buf 0
    gload16(gA0, &Als[0][lo0]); gload16(gA1, &Als[0][lo1]);
    gload16(gB0, &Bls[0][lo0]); gload16(gB1, &Bls[0][lo1]);
    __builtin_amdgcn_s_waitcnt(0);
    __syncthreads();

    for (int kk = 0; kk < 16; ++kk) {
        if (kk < 15) {
            int ko = (kk + 1) * 32;
            int nb = (kk + 1) & 1;
            gload16(gA0 + ko, &Als[nb][lo0]); gload16(gA1 + ko, &Als[nb][lo1]);
            gload16(gB0 + ko, &Bls[nb][lo0]); gload16(gB1 + ko, &Bls[nb][lo1]);
        }
        const unsigned short* Ab = Als[kk & 1];
        const unsigned short* Bb = Bls[kk & 1];
        short8 aF[4], bF[4];
#pragma unroll
        for (int i = 0; i < 4; ++i) {
            aF[i] = *(const short8*)&Ab[(wm + i * 16 + l) * 32 + aswz];
            bF[i] = *(const short8*)&Bb[(wn + i * 16 + l) * 32 + aswz];
        }
        if (!isv) {
#pragma unroll
            for (int mt = 0; mt < 4; ++mt)
#pragma unroll
                for (int nt = 0; nt < 4; ++nt)
                    acc[mt][nt] = __builtin_amdgcn_mfma_f32_16x16x32_bf16(aF[mt], bF[nt], acc[mt][nt], 0, 0, 0);
        } else {
            // swapped: acc rows = n (qd*4+r), cols = o (l)
#pragma unroll
            for (int mt = 0; mt < 4; ++mt)
#pragma unroll
                for (int nt = 0; nt < 4; ++nt)
                    acc[mt][nt] = __builtin_amdgcn_mfma_f32_16x16x32_bf16(bF[nt], aF[mt], acc[mt][nt], 0, 0, 0);
        }
        __builtin_amdgcn_s_waitcnt(0);
        __syncthreads();
    }

    if (!isv) {
        int o_base = m0 + wm;
        int sec = o_base >> 9;             // 0:q 1:k
        int h = (o_base & 511) >> 6;
        float bv[4][4];
#pragma unroll
        for (int mt = 0; mt < 4; ++mt)
#pragma unroll
            for (int r = 0; r < 4; ++r)
                bv[mt][r] = bias[o_base + mt * 16 + qd * 4 + r];
        unsigned short* dst = (sec == 0) ? qT : kT;
        float scl = (sec == 0) ? (0.125f * 1.44269504f) : 1.0f;
#pragma unroll
        for (int mt = 0; mt < 4; ++mt)
#pragma unroll
            for (int nt = 0; nt < 4; ++nt) {
                int n = n0 + wn + nt * 16 + l;
                ushort4 o;
                o.x = f2b((acc[mt][nt][0] + bv[mt][0]) * scl);
                o.y = f2b((acc[mt][nt][1] + bv[mt][1]) * scl);
                o.z = f2b((acc[mt][nt][2] + bv[mt][2]) * scl);
                o.w = f2b((acc[mt][nt][3] + bv[mt][3]) * scl);
                *(ushort4*)(dst + ((size_t)(b * NH_ + h) * N_ + n) * CH_ + mt * 16 + qd * 4) = o;
            }
    } else {
        // V epilogue: rows = n (4 consecutive per reg), cols = ch (lane l) -> ushort4 along n
#pragma unroll
        for (int mt = 0; mt < 4; ++mt) {
            int och = m0 - 1024 + wm + mt * 16;     // + l per lane
            int h = och >> 6;                        // uniform within tile
            int chl = (och & 63) + l;
            float bvl = bias[m0 + wm + mt * 16 + l];
            unsigned short* vdst = vv + ((size_t)(b * NH_ + h) * CH_ + chl) * N_;
#pragma unroll
            for (int nt = 0; nt < 4; ++nt) {
                int n = n0 + wn + nt * 16 + qd * 4;
                ushort4 o;
                o.x = f2b(acc[mt][nt][0] + bvl);
                o.y = f2b(acc[mt][nt][1] + bvl);
                o.z = f2b(acc[mt][nt][2] + bvl);
                o.w = f2b(acc[mt][nt][3] + bvl);
                *(ushort4*)(vdst + n) = o;
            }
        }
    }
}

// ------- Kernel 3: attention; PV = (V as A) x (P as B), K=16 — no transpose, O^T output -------
__global__ __launch_bounds__(256, 4) void attn_kernel(const unsigned short* __restrict__ qT,
                                                      const unsigned short* __restrict__ kT,
                                                      const unsigned short* __restrict__ vv,
                                                      unsigned short* __restrict__ at)
{
    __shared__ unsigned short Ks[2][4096];   // [64 j][64 ch], 16B-block XOR swizzled
    __shared__ unsigned short Vs[2][4224];   // 16 frag-blocks x 264 el; slot=(qd*16+l)*4

    int t = threadIdx.x, lane = t & 63, wv = t >> 6;
    int l = lane & 15, qd = lane >> 4;
    int blk = blockIdx.x;
    int ibk = blk >> 7;
    int bh  = blk & 127;
    int h = bh & 7, b = bh >> 3;
    int i0 = ibk * 128 + wv * 32;
    const size_t hoff = (size_t)bh * (size_t)N_ * CH_;
    const unsigned short* qbase = qT + hoff;
    const unsigned short* kbase = kT + hoff;
    const unsigned short* vbase = vv + hoff;

    short8 qF[2][2];
#pragma unroll
    for (int it = 0; it < 2; ++it)
#pragma unroll
        for (int ks = 0; ks < 2; ++ks)
            qF[it][ks] = *(const short8*)(qbase + (size_t)(i0 + it * 16 + l) * CH_ + ks * 32 + qd * 8);

    int srow = t >> 2, p = t & 3;
    int sw = srow & 7, bb = p * 2;
    int d0 = srow * 64 + ((bb ^ sw) * 8);
    int d1 = srow * 64 + (((bb + 1) ^ sw) * 8);
    int lch = srow & 15, chtS = srow >> 4;
    int vblk = p * 4 + chtS;
    int vd[4];
#pragma unroll
    for (int w = 0; w < 4; ++w)
        vd[w] = vblk * 264 + (w * 16 + lch) * 4;
    const unsigned short* kSrc = kbase + (size_t)srow * CH_ + p * 16;
    const unsigned short* vSrc = vbase + (size_t)srow * N_ + p * 16;

    f32x4 Oa[4][2] = {};
    float lsum[2] = {0.f, 0.f};
    int swl = l & 7;

    uint4 ku0, ku1, vu0, vu1;
    {
        const uint4* kp = (const uint4*)(kSrc);
        ku0 = kp[0]; ku1 = kp[1];
        const uint4* vp2 = (const uint4*)(vSrc);
        vu0 = vp2[0]; vu1 = vp2[1];
        *(uint4*)&Ks[0][d0] = ku0; *(uint4*)&Ks[0][d1] = ku1;
        *(uint2*)&Vs[0][vd[0]] = make_uint2(vu0.x, vu0.y);
        *(uint2*)&Vs[0][vd[1]] = make_uint2(vu0.z, vu0.w);
        *(uint2*)&Vs[0][vd[2]] = make_uint2(vu1.x, vu1.y);
        *(uint2*)&Vs[0][vd[3]] = make_uint2(vu1.z, vu1.w);
        kp  = (const uint4*)(kSrc + 4096);
        ku0 = kp[0]; ku1 = kp[1];
        vp2 = (const uint4*)(vSrc + 64);
        vu0 = vp2[0]; vu1 = vp2[1];
    }

    for (int tile = 0; tile < 16; ++tile) {
        __syncthreads();
        if (tile < 15) {
            unsigned short* Kw = Ks[(tile + 1) & 1];
            unsigned short* Vw = Vs[(tile + 1) & 1];
            *(uint4*)&Kw[d0] = ku0; *(uint4*)&Kw[d1] = ku1;
            *(uint2*)&Vw[vd[0]] = make_uint2(vu0.x, vu0.y);
            *(uint2*)&Vw[vd[1]] = make_uint2(vu0.z, vu0.w);
            *(uint2*)&Vw[vd[2]] = make_uint2(vu1.x, vu1.y);
            *(uint2*)&Vw[vd[3]] = make_uint2(vu1.z, vu1.w);
            if (tile < 14) {
                const uint4* kp = (const uint4*)(kSrc + (size_t)(tile + 2) * 4096);
                ku0 = kp[0]; ku1 = kp[1];
                const uint4* vp2 = (const uint4*)(vSrc + (size_t)(tile + 2) * 64);
                vu0 = vp2[0]; vu1 = vp2[1];
            }
        }
        const unsigned short* Kb = Ks[tile & 1];
        const unsigned short* Vb = Vs[tile & 1];
#pragma unroll
        for (int jb = 0; jb < 2; ++jb) {
            short8 kA[2][2];
#pragma unroll
            for (int jt = 0; jt < 2; ++jt)
#pragma unroll
                for (int ks = 0; ks < 2; ++ks)
                    kA[jt][ks] = *(const short8*)&Kb[(jb * 32 + jt * 16 + l) * 64 + (((ks * 4 + qd) ^ swl) * 8)];
            f32x4 Sa[2][2] = {};
#pragma unroll
            for (int jt = 0; jt < 2; ++jt)
#pragma unroll
                for (int it = 0; it < 2; ++it)
#pragma unroll
                    for (int ks = 0; ks < 2; ++ks)
                        Sa[jt][it] = __builtin_amdgcn_mfma_f32_16x16x32_bf16(kA[jt][ks], qF[it][ks], Sa[jt][it], 0, 0, 0);
            unsigned int pk[2][2][2];
#pragma unroll
            for (int jt = 0; jt < 2; ++jt)
#pragma unroll
                for (int it = 0; it < 2; ++it) {
                    float p0 = __builtin_amdgcn_exp2f(Sa[jt][it][0]);
                    float p1 = __builtin_amdgcn_exp2f(Sa[jt][it][1]);
                    float p2 = __builtin_amdgcn_exp2f(Sa[jt][it][2]);
                    float p3 = __builtin_amdgcn_exp2f(Sa[jt][it][3]);
                    lsum[it] += (p0 + p1) + (p2 + p3);
                    pk[jt][it][0] = packtr(p0, p1);
                    pk[jt][it][1] = packtr(p2, p3);
                }
#pragma unroll
            for (int jt = 0; jt < 2; ++jt) {
                short4v vA[4];
#pragma unroll
                for (int cht = 0; cht < 4; ++cht) {
                    union { uint2 u; short4v s; } vr;
                    vr.u = *(const uint2*)&Vb[((jb * 2 + jt) * 4 + cht) * 264 + (qd * 16 + l) * 4];
                    vA[cht] = vr.s;
                }
#pragma unroll
                for (int it = 0; it < 2; ++it) {
                    union { unsigned int u[2]; short4v s; } ap;
                    ap.u[0] = pk[jt][it][0]; ap.u[1] = pk[jt][it][1];
#pragma unroll
                    for (int cht = 0; cht < 4; ++cht)
                        Oa[cht][it] = __builtin_amdgcn_mfma_f32_16x16x16bf16_1k(vA[cht], ap.s, Oa[cht][it], 0, 0, 0);
                }
            }
        }
    }

#pragma unroll
    for (int it = 0; it < 2; ++it) {
        float lt = lsum[it];
        lt += __shfl_xor(lt, 16);
        lt += __shfl_xor(lt, 32);
        float inv = 1.0f / lt;
        int i = i0 + it * 16 + l;
        unsigned short* dst = at + ((size_t)(b * N_ + i)) * C_ + h * CH_;
#pragma unroll
        for (int cht = 0; cht < 4; ++cht) {
            ushort4 o;
            o.x = f2b(Oa[cht][it][0] * inv);
            o.y = f2b(Oa[cht][it][1] * inv);
            o.z = f2b(Oa[cht][it][2] * inv);
            o.w = f2b(Oa[cht][it][3] * inv);
            *(ushort4*)(dst + cht * 16 + qd * 4) = o;
        }
    }
}

// ------- Kernel 4: proj GEMM, double-buffered BK=32 + bias + fp32 residual -> fp32 out -------
__global__ __launch_bounds__(256) void proj_kernel(const unsigned short* __restrict__ w,
                                                   const float* __restrict__ bias,
                                                   const unsigned short* __restrict__ at,
                                                   const float* __restrict__ x,
                                                   float* __restrict__ out)
{
    __shared__ unsigned short Als[2][128 * 32], Bls[2][128 * 32];
    int t = threadIdx.x;
    int n0 = blockIdx.x * 128, m0 = blockIdx.y * 128, b = blockIdx.z;
    int lane = t & 63, wv = t >> 6;
    int l = lane & 15, qd = lane >> 4;
    int wm = (wv >> 1) * 64, wn = (wv & 1) * 64;
    f32x4 acc[4][4] = {};
    const unsigned short* Bbase = at + ((size_t)(b * N_ + n0)) * C_;

    int lr = lane >> 2, bpos = lane & 3;
    int r0 = wv * 32 + lr, r1 = r0 + 16;
    int c0 = (bpos ^ ((r0 >> 1) & 3)) * 8;
    int c1 = (bpos ^ ((r1 >> 1) & 3)) * 8;
    const unsigned short* gA0 = w + (size_t)(m0 + r0) * C_ + c0;
    const unsigned short* gA1 = w + (size_t)(m0 + r1) * C_ + c1;
    const unsigned short* gB0 = Bbase + (size_t)r0 * C_ + c0;
    const unsigned short* gB1 = Bbase + (size_t)r1 * C_ + c1;
    int lo0 = (wv * 32) * 32, lo1 = (wv * 32 + 16) * 32;
    int aswz = (qd ^ ((l >> 1) & 3)) * 8;

    gload16(gA0, &Als[0][lo0]); gload16(gA1, &Als[0][lo1]);
    gload16(gB0, &Bls[0][lo0]); gload16(gB1, &Bls[0][lo1]);
    __builtin_amdgcn_s_waitcnt(0);
    __syncthreads();

    for (int kk = 0; kk < 16; ++kk) {
        if (kk < 15) {
            int ko = (kk + 1) * 32;
            int nb = (kk + 1) & 1;
            gload16(gA0 + ko, &Als[nb][lo0]); gload16(gA1 + ko, &Als[nb][lo1]);
            gload16(gB0 + ko, &Bls[nb][lo0]); gload16(gB1 + ko, &Bls[nb][lo1]);
        }
        const unsigned short* Ab = Als[kk & 1];
        const unsigned short* Bb = Bls[kk & 1];
        short8 aF[4], bF[4];
#pragma unroll
        for (int i = 0; i < 4; ++i) {
            aF[i] = *(const short8*)&Ab[(wm + i * 16 + l) * 32 + aswz];
            bF[i] = *(const short8*)&Bb[(wn + i * 16 + l) * 32 + aswz];
        }
#pragma unroll
        for (int mt = 0; mt < 4; ++mt)
#pragma unroll
            for (int nt = 0; nt < 4; ++nt)
                acc[mt][nt] = __builtin_amdgcn_mfma_f32_16x16x32_bf16(aF[mt], bF[nt], acc[mt][nt], 0, 0, 0);
        __builtin_amdgcn_s_waitcnt(0);
        __syncthreads();
    }

    float bv[4][4];
#pragma unroll
    for (int mt = 0; mt < 4; ++mt)
#pragma unroll
        for (int r = 0; r < 4; ++r)
            bv[mt][r] = bias[m0 + wm + mt * 16 + qd * 4 + r];

#pragma unroll
    for (int mt = 0; mt < 4; ++mt)
#pragma unroll
        for (int nt = 0; nt < 4; ++nt) {
            int n = n0 + wn + nt * 16 + l;
#pragma unroll
            for (int r = 0; r < 4; ++r) {
                int o = m0 + wm + mt * 16 + qd * 4 + r;
                size_t idx = ((size_t)b * C_ + o) * N_ + n;
                out[idx] = acc[mt][nt][r] + bv[mt][r] + x[idx];
            }
        }
}

extern "C" void kernel_launch(void* const* d_in, const int* in_sizes, int n_in,
                              void* d_out, int out_size, void* d_ws, size_t ws_size,
                              hipStream_t stream) {
    const float* x     = (const float*)d_in[0];
    const float* nw    = (const float*)d_in[1];
    const float* nb    = (const float*)d_in[2];
    const float* qkvw  = (const float*)d_in[3];
    const float* qkvb  = (const float*)d_in[4];
    const float* projw = (const float*)d_in[5];
    const float* projb = (const float*)d_in[6];
    float* out = (float*)d_out;
    char* ws = (char*)d_ws;
    const size_t SZ = (size_t)B_ * N_ * C_ * 2;
    unsigned short* xnT = (unsigned short*)(ws);
    unsigned short* qTp = (unsigned short*)(ws + SZ);
    unsigned short* kTp = (unsigned short*)(ws + 2 * SZ);
    unsigned short* vp  = (unsigned short*)(ws + 3 * SZ);
    unsigned short* atp = (unsigned short*)(ws);          // alias xnT: dead after qkv_kernel
    unsigned short* wq  = (unsigned short*)(ws + 4 * SZ);
    unsigned short* wp  = (unsigned short*)(ws + 4 * SZ + (size_t)3 * C_ * C_ * 2);

    hipLaunchKernelGGL(gnconv_kernel, dim3(1024), dim3(256), 0, stream, x, nw, nb, xnT, qkvw, projw, wq, wp);
    hipLaunchKernelGGL(qkv_kernel,    dim3(8, 12, B_), dim3(256), 0, stream, wq, qkvb, xnT, qTp, kTp, vp);
    hipLaunchKernelGGL(attn_kernel,   dim3(1024), dim3(256), 0, stream, qTp, kTp, vp, atp);
    hipLaunchKernelGGL(proj_kernel,   dim3(8, 4, B_), dim3(256), 0, stream, wp, projb, atp, x, out);
}

// Round 11
// 207.181 us; speedup vs baseline: 1.1238x; 1.1238x over previous
//
#include <hip/hip_runtime.h>

typedef short short8 __attribute__((ext_vector_type(8)));
typedef short short4v __attribute__((ext_vector_type(4)));
typedef float f32x4 __attribute__((ext_vector_type(4)));

#define B_   16
#define C_   512
#define N_   1024
#define NH_  8
#define CH_  64
#define G_   32
#define CPG_ 16

__device__ inline float b2f(unsigned int u) {
    union { unsigned int i; float f; } v; v.i = u << 16; return v.f;
}
__device__ inline unsigned short f2b(float f) {
    union { float f; unsigned int i; } v; v.f = f;
    unsigned int r = v.i + 0x7fffu + ((v.i >> 16) & 1u);
    return (unsigned short)(r >> 16);
}
__device__ inline unsigned int pack2(float a, float b) {
    return (unsigned int)f2b(a) | ((unsigned int)f2b(b) << 16);
}
__device__ inline unsigned int asu(float f) {
    union { float f; unsigned int i; } v; v.f = f; return v.i;
}
// truncating bf16 pack: [lo16 = hi16(a) | hi16(b)<<16]
__device__ inline unsigned int packtr(float a, float b) {
    return __builtin_amdgcn_perm(asu(b), asu(a), 0x07060302u);
}
// async global->LDS, 16B per lane; LDS dst = wave-uniform base + lane*16
__device__ inline void gload16(const void* g, void* l) {
    __builtin_amdgcn_global_load_lds(
        (const __attribute__((address_space(1))) void*)g,
        (__attribute__((address_space(3))) void*)l, 16, 0, 0);
}

// ------- Kernel 1: single-pass GroupNorm (blocks 0-511) | weight conv (512-1023) -------
// x cached in registers (64 floats/lane): one HBM read, stats + normalize in one pass.
__global__ __launch_bounds__(256) void gnconv_kernel(const float* __restrict__ x,
                                                     const float* __restrict__ nw,
                                                     const float* __restrict__ nb,
                                                     unsigned short* __restrict__ xnT,
                                                     const float* __restrict__ qkvw,
                                                     const float* __restrict__ projw,
                                                     unsigned short* __restrict__ wq,
                                                     unsigned short* __restrict__ wp)
{
    __shared__ float red[8];
    int t = threadIdx.x;

    if (blockIdx.x >= 512) {
        const int NQ = 3 * C_ * C_;
        int idx = (((int)blockIdx.x - 512) * 256 + t) * 8;
        const float* src; unsigned short* dst; int j;
        if (idx < NQ) { src = qkvw;  dst = wq; j = idx; }
        else          { src = projw; dst = wp; j = idx - NQ; }
        float4 u0 = *(const float4*)(src + j);
        float4 u1 = *(const float4*)(src + j + 4);
        uint4 p;
        p.x = pack2(u0.x, u0.y); p.y = pack2(u0.z, u0.w);
        p.z = pack2(u1.x, u1.y); p.w = pack2(u1.z, u1.w);
        *(uint4*)(dst + j) = p;
        return;
    }

    int b = blockIdx.x >> 5, g = blockIdx.x & 31;
    const float* base = x + ((size_t)(b * C_ + g * CPG_)) * N_;

    // one pass: lane owns 4 columns (t*2, t*2+1, 512+t*2, 512+t*2+1) x 16 ch
    float2 v[2][16];
    float s = 0.f, ss = 0.f;
#pragma unroll
    for (int nbi = 0; nbi < 2; ++nbi)
#pragma unroll
        for (int ch = 0; ch < 16; ++ch) {
            float2 u = *(const float2*)(base + (size_t)ch * N_ + nbi * 512 + t * 2);
            v[nbi][ch] = u;
            s  += u.x + u.y;
            ss += u.x * u.x + u.y * u.y;
        }
#pragma unroll
    for (int off = 1; off < 64; off <<= 1) {
        s  += __shfl_xor(s, off);
        ss += __shfl_xor(ss, off);
    }
    int wv = t >> 6;
    if ((t & 63) == 0) { red[wv * 2] = s; red[wv * 2 + 1] = ss; }
    __syncthreads();
    s  = red[0] + red[2] + red[4] + red[6];
    ss = red[1] + red[3] + red[5] + red[7];
    float mean = s * (1.f / 16384.f);
    float var  = ss * (1.f / 16384.f) - mean * mean;
    float rstd = rsqrtf(var + 1e-5f);

    float sc[16], sh[16];
#pragma unroll
    for (int ch = 0; ch < 16; ++ch) {
        sc[ch] = nw[g * CPG_ + ch] * rstd;
        sh[ch] = nb[g * CPG_ + ch] - mean * sc[ch];
    }

#pragma unroll
    for (int nbi = 0; nbi < 2; ++nbi) {
        int n = nbi * 512 + t * 2;
#pragma unroll
        for (int col = 0; col < 2; ++col) {
            float f[16];
#pragma unroll
            for (int ch = 0; ch < 16; ++ch) {
                float xv = col ? v[nbi][ch].y : v[nbi][ch].x;
                f[ch] = xv * sc[ch] + sh[ch];
            }
            uint4 o0, o1;
            o0.x = pack2(f[0], f[1]);  o0.y = pack2(f[2], f[3]);
            o0.z = pack2(f[4], f[5]);  o0.w = pack2(f[6], f[7]);
            o1.x = pack2(f[8], f[9]);  o1.y = pack2(f[10], f[11]);
            o1.z = pack2(f[12], f[13]); o1.w = pack2(f[14], f[15]);
            unsigned short* dst = xnT + ((size_t)(b * N_ + n + col)) * C_ + g * CPG_;
            *(uint4*)dst = o0;
            *(uint4*)(dst + 8) = o1;
        }
    }
}

// ------- Kernel 2: QKV GEMM, BK=64 single-buffer (R9) + swapped-operand V path -------
__global__ __launch_bounds__(256) void qkv_kernel(const unsigned short* __restrict__ w,
                                                  const float* __restrict__ bias,
                                                  const unsigned short* __restrict__ xnT,
                                                  unsigned short* __restrict__ qT,
                                                  unsigned short* __restrict__ kT,
                                                  unsigned short* __restrict__ vv)
{
    __shared__ unsigned short Als[128 * 64], Bls[128 * 64];
    int t = threadIdx.x;
    int n0 = blockIdx.x * 128, m0 = blockIdx.y * 128, b = blockIdx.z;
    int lane = t & 63, wv = t >> 6;
    int l = lane & 15, qd = lane >> 4;
    int wm = (wv >> 1) * 64, wn = (wv & 1) * 64;
    f32x4 acc[4][4] = {};
    const unsigned short* Bbase = xnT + ((size_t)(b * N_ + n0)) * C_;
    int isv = (m0 >= 1024);   // V section: swap MFMA operands

    int grow = lane >> 3, gcol = ((lane & 7) ^ grow) * 8;
    const unsigned short* pA[4]; const unsigned short* pB[4];
    unsigned short* lA[4]; unsigned short* lB[4];
#pragma unroll
    for (int g = 0; g < 4; ++g) {
        int r = wv * 32 + g * 8 + grow;
        pA[g] = w + (size_t)(m0 + r) * C_ + gcol;
        pB[g] = Bbase + (size_t)r * C_ + gcol;
        lA[g] = &Als[(wv * 32 + g * 8) * 64];
        lB[g] = &Bls[(wv * 32 + g * 8) * 64];
    }

    for (int kk = 0; kk < 8; ++kk) {
        int ko = kk * 64;
#pragma unroll
        for (int g = 0; g < 4; ++g) {
            gload16(pA[g] + ko, lA[g]);
            gload16(pB[g] + ko, lB[g]);
        }
        __builtin_amdgcn_s_waitcnt(0);
        __syncthreads();
#pragma unroll
        for (int ks = 0; ks < 2; ++ks) {
            short8 aF[4], bF[4];
#pragma unroll
            for (int i = 0; i < 4; ++i) {
                int ra = wm + i * 16 + l;
                aF[i] = *(const short8*)&Als[ra * 64 + (((ks * 4 + qd) ^ (l & 7)) * 8)];
                int rb = wn + i * 16 + l;
                bF[i] = *(const short8*)&Bls[rb * 64 + (((ks * 4 + qd) ^ (l & 7)) * 8)];
            }
            if (!isv) {
#pragma unroll
                for (int mt = 0; mt < 4; ++mt)
#pragma unroll
                    for (int nt = 0; nt < 4; ++nt)
                        acc[mt][nt] = __builtin_amdgcn_mfma_f32_16x16x32_bf16(aF[mt], bF[nt], acc[mt][nt], 0, 0, 0);
            } else {
                // swapped: acc rows = n (qd*4+r), cols = o (l)
#pragma unroll
                for (int mt = 0; mt < 4; ++mt)
#pragma unroll
                    for (int nt = 0; nt < 4; ++nt)
                        acc[mt][nt] = __builtin_amdgcn_mfma_f32_16x16x32_bf16(bF[nt], aF[mt], acc[mt][nt], 0, 0, 0);
            }
        }
        __syncthreads();
    }

    if (!isv) {
        int o_base = m0 + wm;
        int sec = o_base >> 9;             // 0:q 1:k
        int h = (o_base & 511) >> 6;
        float bv[4][4];
#pragma unroll
        for (int mt = 0; mt < 4; ++mt)
#pragma unroll
            for (int r = 0; r < 4; ++r)
                bv[mt][r] = bias[o_base + mt * 16 + qd * 4 + r];
        unsigned short* dst = (sec == 0) ? qT : kT;
        float scl = (sec == 0) ? (0.125f * 1.44269504f) : 1.0f;
#pragma unroll
        for (int mt = 0; mt < 4; ++mt)
#pragma unroll
            for (int nt = 0; nt < 4; ++nt) {
                int n = n0 + wn + nt * 16 + l;
                ushort4 o;
                o.x = f2b((acc[mt][nt][0] + bv[mt][0]) * scl);
                o.y = f2b((acc[mt][nt][1] + bv[mt][1]) * scl);
                o.z = f2b((acc[mt][nt][2] + bv[mt][2]) * scl);
                o.w = f2b((acc[mt][nt][3] + bv[mt][3]) * scl);
                *(ushort4*)(dst + ((size_t)(b * NH_ + h) * N_ + n) * CH_ + mt * 16 + qd * 4) = o;
            }
    } else {
        // V epilogue (swapped acc): rows = n, cols = ch(l) -> coalesced ushort4 along n
#pragma unroll
        for (int mt = 0; mt < 4; ++mt) {
            int och = m0 - 1024 + wm + mt * 16;      // + l per lane
            int h = och >> 6;                         // uniform within 16-block
            int chl = (och & 63) + l;
            float bvl = bias[m0 + wm + mt * 16 + l];
            unsigned short* vdst = vv + ((size_t)(b * NH_ + h) * CH_ + chl) * N_;
#pragma unroll
            for (int nt = 0; nt < 4; ++nt) {
                int n = n0 + wn + nt * 16 + qd * 4;
                ushort4 o;
                o.x = f2b(acc[mt][nt][0] + bvl);
                o.y = f2b(acc[mt][nt][1] + bvl);
                o.z = f2b(acc[mt][nt][2] + bvl);
                o.w = f2b(acc[mt][nt][3] + bvl);
                *(ushort4*)(vdst + n) = o;
            }
        }
    }
}

// ------- Kernel 3: attention; PV = (V as A) x (P as B), K=16 — no transpose, O^T output -------
__global__ __launch_bounds__(256, 4) void attn_kernel(const unsigned short* __restrict__ qT,
                                                      const unsigned short* __restrict__ kT,
                                                      const unsigned short* __restrict__ vv,
                                                      unsigned short* __restrict__ at)
{
    __shared__ unsigned short Ks[2][4096];   // [64 j][64 ch], 16B-block XOR swizzled
    __shared__ unsigned short Vs[2][4224];   // 16 frag-blocks x 264 el; slot=(qd*16+l)*4

    int t = threadIdx.x, lane = t & 63, wv = t >> 6;
    int l = lane & 15, qd = lane >> 4;
    int blk = blockIdx.x;
    int ibk = blk >> 7;
    int bh  = blk & 127;
    int h = bh & 7, b = bh >> 3;
    int i0 = ibk * 128 + wv * 32;
    const size_t hoff = (size_t)bh * (size_t)N_ * CH_;
    const unsigned short* qbase = qT + hoff;
    const unsigned short* kbase = kT + hoff;
    const unsigned short* vbase = vv + hoff;

    short8 qF[2][2];
#pragma unroll
    for (int it = 0; it < 2; ++it)
#pragma unroll
        for (int ks = 0; ks < 2; ++ks)
            qF[it][ks] = *(const short8*)(qbase + (size_t)(i0 + it * 16 + l) * CH_ + ks * 32 + qd * 8);

    int srow = t >> 2, p = t & 3;
    int sw = srow & 7, bb = p * 2;
    int d0 = srow * 64 + ((bb ^ sw) * 8);
    int d1 = srow * 64 + (((bb + 1) ^ sw) * 8);
    int lch = srow & 15, chtS = srow >> 4;
    int vblk = p * 4 + chtS;
    int vd[4];
#pragma unroll
    for (int w = 0; w < 4; ++w)
        vd[w] = vblk * 264 + (w * 16 + lch) * 4;
    const unsigned short* kSrc = kbase + (size_t)srow * CH_ + p * 16;
    const unsigned short* vSrc = vbase + (size_t)srow * N_ + p * 16;

    f32x4 Oa[4][2] = {};
    float lsum[2] = {0.f, 0.f};
    int swl = l & 7;

    uint4 ku0, ku1, vu0, vu1;
    {
        const uint4* kp = (const uint4*)(kSrc);
        ku0 = kp[0]; ku1 = kp[1];
        const uint4* vp2 = (const uint4*)(vSrc);
        vu0 = vp2[0]; vu1 = vp2[1];
        *(uint4*)&Ks[0][d0] = ku0; *(uint4*)&Ks[0][d1] = ku1;
        *(uint2*)&Vs[0][vd[0]] = make_uint2(vu0.x, vu0.y);
        *(uint2*)&Vs[0][vd[1]] = make_uint2(vu0.z, vu0.w);
        *(uint2*)&Vs[0][vd[2]] = make_uint2(vu1.x, vu1.y);
        *(uint2*)&Vs[0][vd[3]] = make_uint2(vu1.z, vu1.w);
        kp  = (const uint4*)(kSrc + 4096);
        ku0 = kp[0]; ku1 = kp[1];
        vp2 = (const uint4*)(vSrc + 64);
        vu0 = vp2[0]; vu1 = vp2[1];
    }

    for (int tile = 0; tile < 16; ++tile) {
        __syncthreads();
        if (tile < 15) {
            unsigned short* Kw = Ks[(tile + 1) & 1];
            unsigned short* Vw = Vs[(tile + 1) & 1];
            *(uint4*)&Kw[d0] = ku0; *(uint4*)&Kw[d1] = ku1;
            *(uint2*)&Vw[vd[0]] = make_uint2(vu0.x, vu0.y);
            *(uint2*)&Vw[vd[1]] = make_uint2(vu0.z, vu0.w);
            *(uint2*)&Vw[vd[2]] = make_uint2(vu1.x, vu1.y);
            *(uint2*)&Vw[vd[3]] = make_uint2(vu1.z, vu1.w);
            if (tile < 14) {
                const uint4* kp = (const uint4*)(kSrc + (size_t)(tile + 2) * 4096);
                ku0 = kp[0]; ku1 = kp[1];
                const uint4* vp2 = (const uint4*)(vSrc + (size_t)(tile + 2) * 64);
                vu0 = vp2[0]; vu1 = vp2[1];
            }
        }
        const unsigned short* Kb = Ks[tile & 1];
        const unsigned short* Vb = Vs[tile & 1];
#pragma unroll
        for (int jb = 0; jb < 2; ++jb) {
            short8 kA[2][2];
#pragma unroll
            for (int jt = 0; jt < 2; ++jt)
#pragma unroll
                for (int ks = 0; ks < 2; ++ks)
                    kA[jt][ks] = *(const short8*)&Kb[(jb * 32 + jt * 16 + l) * 64 + (((ks * 4 + qd) ^ swl) * 8)];
            f32x4 Sa[2][2] = {};
#pragma unroll
            for (int jt = 0; jt < 2; ++jt)
#pragma unroll
                for (int it = 0; it < 2; ++it)
#pragma unroll
                    for (int ks = 0; ks < 2; ++ks)
                        Sa[jt][it] = __builtin_amdgcn_mfma_f32_16x16x32_bf16(kA[jt][ks], qF[it][ks], Sa[jt][it], 0, 0, 0);
            unsigned int pk[2][2][2];
#pragma unroll
            for (int jt = 0; jt < 2; ++jt)
#pragma unroll
                for (int it = 0; it < 2; ++it) {
                    float p0 = __builtin_amdgcn_exp2f(Sa[jt][it][0]);
                    float p1 = __builtin_amdgcn_exp2f(Sa[jt][it][1]);
                    float p2 = __builtin_amdgcn_exp2f(Sa[jt][it][2]);
                    float p3 = __builtin_amdgcn_exp2f(Sa[jt][it][3]);
                    lsum[it] += (p0 + p1) + (p2 + p3);
                    pk[jt][it][0] = packtr(p0, p1);
                    pk[jt][it][1] = packtr(p2, p3);
                }
#pragma unroll
            for (int jt = 0; jt < 2; ++jt) {
                short4v vA[4];
#pragma unroll
                for (int cht = 0; cht < 4; ++cht) {
                    union { uint2 u; short4v s; } vr;
                    vr.u = *(const uint2*)&Vb[((jb * 2 + jt) * 4 + cht) * 264 + (qd * 16 + l) * 4];
                    vA[cht] = vr.s;
                }
#pragma unroll
                for (int it = 0; it < 2; ++it) {
                    union { unsigned int u[2]; short4v s; } ap;
                    ap.u[0] = pk[jt][it][0]; ap.u[1] = pk[jt][it][1];
#pragma unroll
                    for (int cht = 0; cht < 4; ++cht)
                        Oa[cht][it] = __builtin_amdgcn_mfma_f32_16x16x16bf16_1k(vA[cht], ap.s, Oa[cht][it], 0, 0, 0);
                }
            }
        }
    }

#pragma unroll
    for (int it = 0; it < 2; ++it) {
        float lt = lsum[it];
        lt += __shfl_xor(lt, 16);
        lt += __shfl_xor(lt, 32);
        float inv = 1.0f / lt;
        int i = i0 + it * 16 + l;
        unsigned short* dst = at + ((size_t)(b * N_ + i)) * C_ + h * CH_;
#pragma unroll
        for (int cht = 0; cht < 4; ++cht) {
            ushort4 o;
            o.x = f2b(Oa[cht][it][0] * inv);
            o.y = f2b(Oa[cht][it][1] * inv);
            o.z = f2b(Oa[cht][it][2] * inv);
            o.w = f2b(Oa[cht][it][3] * inv);
            *(ushort4*)(dst + cht * 16 + qd * 4) = o;
        }
    }
}

// ------- Kernel 4: proj GEMM, BK=64 single-buffer (R9) + bias + fp32 residual -------
__global__ __launch_bounds__(256) void proj_kernel(const unsigned short* __restrict__ w,
                                                   const float* __restrict__ bias,
                                                   const unsigned short* __restrict__ at,
                                                   const float* __restrict__ x,
                                                   float* __restrict__ out)
{
    __shared__ unsigned short Als[128 * 64], Bls[128 * 64];
    int t = threadIdx.x;
    int n0 = blockIdx.x * 128, m0 = blockIdx.y * 128, b = blockIdx.z;
    int lane = t & 63, wv = t >> 6;
    int l = lane & 15, qd = lane >> 4;
    int wm = (wv >> 1) * 64, wn = (wv & 1) * 64;
    f32x4 acc[4][4] = {};
    const unsigned short* Bbase = at + ((size_t)(b * N_ + n0)) * C_;

    int grow = lane >> 3, gcol = ((lane & 7) ^ grow) * 8;
    const unsigned short* pA[4]; const unsigned short* pB[4];
    unsigned short* lA[4]; unsigned short* lB[4];
#pragma unroll
    for (int g = 0; g < 4; ++g) {
        int r = wv * 32 + g * 8 + grow;
        pA[g] = w + (size_t)(m0 + r) * C_ + gcol;
        pB[g] = Bbase + (size_t)r * C_ + gcol;
        lA[g] = &Als[(wv * 32 + g * 8) * 64];
        lB[g] = &Bls[(wv * 32 + g * 8) * 64];
    }

    for (int kk = 0; kk < 8; ++kk) {
        int ko = kk * 64;
#pragma unroll
        for (int g = 0; g < 4; ++g) {
            gload16(pA[g] + ko, lA[g]);
            gload16(pB[g] + ko, lB[g]);
        }
        __builtin_amdgcn_s_waitcnt(0);
        __syncthreads();
#pragma unroll
        for (int ks = 0; ks < 2; ++ks) {
            short8 aF[4], bF[4];
#pragma unroll
            for (int i = 0; i < 4; ++i) {
                int ra = wm + i * 16 + l;
                aF[i] = *(const short8*)&Als[ra * 64 + (((ks * 4 + qd) ^ (l & 7)) * 8)];
                int rb = wn + i * 16 + l;
                bF[i] = *(const short8*)&Bls[rb * 64 + (((ks * 4 + qd) ^ (l & 7)) * 8)];
            }
#pragma unroll
            for (int mt = 0; mt < 4; ++mt)
#pragma unroll
                for (int nt = 0; nt < 4; ++nt)
                    acc[mt][nt] = __builtin_amdgcn_mfma_f32_16x16x32_bf16(aF[mt], bF[nt], acc[mt][nt], 0, 0, 0);
        }
        __syncthreads();
    }

    float bv[4][4];
#pragma unroll
    for (int mt = 0; mt < 4; ++mt)
#pragma unroll
        for (int r = 0; r < 4; ++r)
            bv[mt][r] = bias[m0 + wm + mt * 16 + qd * 4 + r];

#pragma unroll
    for (int mt = 0; mt < 4; ++mt)
#pragma unroll
        for (int nt = 0; nt < 4; ++nt) {
            int n = n0 + wn + nt * 16 + l;
#pragma unroll
            for (int r = 0; r < 4; ++r) {
                int o = m0 + wm + mt * 16 + qd * 4 + r;
                size_t idx = ((size_t)b * C_ + o) * N_ + n;
                out[idx] = acc[mt][nt][r] + bv[mt][r] + x[idx];
            }
        }
}

extern "C" void kernel_launch(void* const* d_in, const int* in_sizes, int n_in,
                              void* d_out, int out_size, void* d_ws, size_t ws_size,
                              hipStream_t stream) {
    const float* x     = (const float*)d_in[0];
    const float* nw    = (const float*)d_in[1];
    const float* nb    = (const float*)d_in[2];
    const float* qkvw  = (const float*)d_in[3];
    const float* qkvb  = (const float*)d_in[4];
    const float* projw = (const float*)d_in[5];
    const float* projb = (const float*)d_in[6];
    float* out = (float*)d_out;
    char* ws = (char*)d_ws;
    const size_t SZ = (size_t)B_ * N_ * C_ * 2;
    unsigned short* xnT = (unsigned short*)(ws);
    unsigned short* qTp = (unsigned short*)(ws + SZ);
    unsigned short* kTp = (unsigned short*)(ws + 2 * SZ);
    unsigned short* vp  = (unsigned short*)(ws + 3 * SZ);
    unsigned short* atp = (unsigned short*)(ws);          // alias xnT: dead after qkv_kernel
    unsigned short* wq  = (unsigned short*)(ws + 4 * SZ);
    unsigned short* wp  = (unsigned short*)(ws + 4 * SZ + (size_t)3 * C_ * C_ * 2);

    hipLaunchKernelGGL(gnconv_kernel, dim3(1024), dim3(256), 0, stream, x, nw, nb, xnT, qkvw, projw, wq, wp);
    hipLaunchKernelGGL(qkv_kernel,    dim3(8, 12, B_), dim3(256), 0, stream, wq, qkvb, xnT, qTp, kTp, vp);
    hipLaunchKernelGGL(attn_kernel,   dim3(1024), dim3(256), 0, stream, qTp, kTp, vp, atp);
    hipLaunchKernelGGL(proj_kernel,   dim3(8, 4, B_), dim3(256), 0, stream, wp, projb, atp, x, out);
}